// Round 2
// baseline (336.924 us; speedup 1.0000x reference)
//
#include <hip/hip_runtime.h>

#define N_NODES 10000
#define HID 512
#define MPAD 10112          // 79 * 128
#define N_GRAPHS 64
#define N_CLASSES 10

typedef __bf16 bf16_t;
typedef __bf16 bf16x8 __attribute__((ext_vector_type(8)));
typedef float  f32x4  __attribute__((ext_vector_type(4)));

// ---------------------------------------------------------------------------
// Input conversion: x (fp32) -> bf16 hi/lo pair (3-term split GEMM precision)
// ---------------------------------------------------------------------------
__global__ void conv_x(const float* __restrict__ x,
                       bf16_t* __restrict__ xh, bf16_t* __restrict__ xl) {
    int idx = (blockIdx.x * 256 + threadIdx.x) * 8;   // < N_NODES*HID
    f32x4 v0 = *(const f32x4*)&x[idx];
    f32x4 v1 = *(const f32x4*)&x[idx + 4];
    float v[8] = {v0[0], v0[1], v0[2], v0[3], v1[0], v1[1], v1[2], v1[3]};
    bf16x8 hi, lo;
#pragma unroll
    for (int j = 0; j < 8; ++j) {
        bf16_t h = (bf16_t)v[j];
        hi[j] = h;
        lo[j] = (bf16_t)(v[j] - (float)h);
    }
    *(bf16x8*)&xh[idx] = hi;
    *(bf16x8*)&xl[idx] = lo;
}

// W [3][512][512] row-major (W[l][k][j]) -> transposed bf16 hi/lo: WT[l][j][k]
__global__ void conv_w(const float* __restrict__ W,
                       bf16_t* __restrict__ whT, bf16_t* __restrict__ wlT) {
    int o   = blockIdx.x * 256 + threadIdx.x;  // < 3*512*512, output-indexed
    int lyr = o >> 18;
    int rem = o & 262143;
    int j   = rem >> 9;
    int k   = rem & 511;
    float v = W[(lyr << 18) + (k << 9) + j];
    bf16_t h = (bf16_t)v;
    whT[o] = h;
    wlT[o] = (bf16_t)(v - (float)h);
}

// ---------------------------------------------------------------------------
// Degree + CSR build (grouped by target col), no fp32 atomics in hot path
// ---------------------------------------------------------------------------
__global__ void count_deg(const int* __restrict__ col, int* __restrict__ cnt, int E) {
    int e = blockIdx.x * 256 + threadIdx.x;
    if (e < E) atomicAdd(&cnt[col[e]], 1);
}

__global__ void dinv_k(const int* __restrict__ cnt, float* __restrict__ dinv) {
    int n = blockIdx.x * 256 + threadIdx.x;
    if (n < N_NODES) dinv[n] = rsqrtf(1.0f + (float)cnt[n]);  // +1 self-loop
}

__global__ __launch_bounds__(1024) void scan_k(const int* __restrict__ cnt,
                                               int* __restrict__ off) {
    __shared__ int s[1024];
    int t = threadIdx.x;
    int base = t * 10;
    int loc[10];
    int sum = 0;
#pragma unroll
    for (int j = 0; j < 10; ++j) {
        int n = base + j;
        int v = (n < N_NODES) ? cnt[n] : 0;
        loc[j] = sum;
        sum += v;
    }
    s[t] = sum;
    __syncthreads();
    for (int o = 1; o < 1024; o <<= 1) {
        int v = (t >= o) ? s[t - o] : 0;
        __syncthreads();
        s[t] += v;
        __syncthreads();
    }
    int pre = (t > 0) ? s[t - 1] : 0;
#pragma unroll
    for (int j = 0; j < 10; ++j) {
        int n = base + j;
        if (n <= N_NODES) off[n] = pre + loc[j];
    }
}

__global__ void scatter_k(const int* __restrict__ row, const int* __restrict__ col,
                          const int* __restrict__ off, int* __restrict__ cursor,
                          const float* __restrict__ dinv,
                          int* __restrict__ csrc, float* __restrict__ cw, int E) {
    int e = blockIdx.x * 256 + threadIdx.x;
    if (e >= E) return;
    int c = col[e], r = row[e];
    int p = off[c] + atomicAdd(&cursor[c], 1);
    csrc[p] = r;
    cw[p]   = dinv[r] * dinv[c];
}

// ---------------------------------------------------------------------------
// GEMM: h[MPAD][512] = (xh+xl) @ (Wh+Wl)  via 3-term bf16 MFMA split
// 128x128 block tile, 4 waves (2x2), 64x64 per wave, BK=32, single-buffer LDS
// ---------------------------------------------------------------------------
__global__ __launch_bounds__(256) void gemm3(
    const bf16_t* __restrict__ xh, const bf16_t* __restrict__ xl,
    const bf16_t* __restrict__ wh, const bf16_t* __restrict__ wl,  // [512][512] = W^T[j][k]
    float* __restrict__ hout)
{
    __shared__ alignas(16) bf16_t sAh[128 * 32];
    __shared__ alignas(16) bf16_t sAl[128 * 32];
    __shared__ alignas(16) bf16_t sBh[128 * 32];
    __shared__ alignas(16) bf16_t sBl[128 * 32];

    const int t  = threadIdx.x;
    const int l  = t & 63;
    const int wv = t >> 6;
    const int wr = wv >> 1;   // 0..1
    const int wc = wv & 1;    // 0..1
    const int m0 = blockIdx.x * 128;
    const int n0 = blockIdx.y * 128;

    f32x4 acc[4][4];
#pragma unroll
    for (int m = 0; m < 4; ++m)
#pragma unroll
        for (int n = 0; n < 4; ++n) acc[m][n] = (f32x4){0.f, 0.f, 0.f, 0.f};

    const int lr  = l & 15;
    const int kgr = (l >> 4) * 8;   // k-group start within BK=32

    for (int kk = 0; kk < HID; kk += 32) {
        __syncthreads();  // previous iter's readers done before overwrite
#pragma unroll
        for (int i = 0; i < 2; ++i) {
            int b  = (t + i * 256) * 16;   // byte within the 8KB tile
            int r  = b >> 6;               // tile row (64B per row of 32 bf16)
            int ce = (b & 63) >> 1;        // element offset within row
            size_t gA = (size_t)(m0 + r) * HID + kk + ce;
            size_t gB = (size_t)(n0 + r) * HID + kk + ce;
            *(bf16x8*)&sAh[r * 32 + ce] = *(const bf16x8*)&xh[gA];
            *(bf16x8*)&sAl[r * 32 + ce] = *(const bf16x8*)&xl[gA];
            *(bf16x8*)&sBh[r * 32 + ce] = *(const bf16x8*)&wh[gB];
            *(bf16x8*)&sBl[r * 32 + ce] = *(const bf16x8*)&wl[gB];
        }
        __syncthreads();

        bf16x8 ah[4], al[4], bh[4], bl[4];
#pragma unroll
        for (int m = 0; m < 4; ++m) {
            int row = wr * 64 + m * 16 + lr;
            ah[m] = *(const bf16x8*)&sAh[row * 32 + kgr];
            al[m] = *(const bf16x8*)&sAl[row * 32 + kgr];
        }
#pragma unroll
        for (int n = 0; n < 4; ++n) {
            int col = wc * 64 + n * 16 + lr;
            bh[n] = *(const bf16x8*)&sBh[col * 32 + kgr];
            bl[n] = *(const bf16x8*)&sBl[col * 32 + kgr];
        }
#pragma unroll
        for (int m = 0; m < 4; ++m)
#pragma unroll
            for (int n = 0; n < 4; ++n) {
                acc[m][n] = __builtin_amdgcn_mfma_f32_16x16x32_bf16(ah[m], bh[n], acc[m][n], 0, 0, 0);
                acc[m][n] = __builtin_amdgcn_mfma_f32_16x16x32_bf16(al[m], bh[n], acc[m][n], 0, 0, 0);
                acc[m][n] = __builtin_amdgcn_mfma_f32_16x16x32_bf16(ah[m], bl[n], acc[m][n], 0, 0, 0);
            }
    }

    // C/D layout (m89-verified): col = l&15, row = (l>>4)*4 + r
    const int rq = (l >> 4) * 4;
#pragma unroll
    for (int m = 0; m < 4; ++m) {
        int row = m0 + wr * 64 + m * 16 + rq;
#pragma unroll
        for (int n = 0; n < 4; ++n) {
            int col = n0 + wc * 64 + n * 16 + lr;
#pragma unroll
            for (int r = 0; r < 4; ++r)
                hout[(size_t)(row + r) * HID + col] = acc[m][n][r];
        }
    }
}

// ---------------------------------------------------------------------------
// Aggregation: out[n] = relu( sum_{e->n} w_e * h[src_e] + dinv[n]^2 * h[n] + b )
// one wave per node, lane owns 8 contiguous fp32 cols
// ---------------------------------------------------------------------------
template <bool LAST>
__global__ __launch_bounds__(256) void agg_k(
    const float* __restrict__ h, const int* __restrict__ off,
    const int* __restrict__ csrc, const float* __restrict__ cw,
    const float* __restrict__ dinv, const float* __restrict__ bias,
    bf16_t* __restrict__ xh, bf16_t* __restrict__ xl, float* __restrict__ x3)
{
    int node = blockIdx.x * 4 + (threadIdx.x >> 6);
    if (node >= N_NODES) return;
    int l  = threadIdx.x & 63;
    int c0 = l * 8;

    float dn = dinv[node];
    float sw = dn * dn;
    const float* hr = h + (size_t)node * HID + c0;
    f32x4 a0 = *(const f32x4*)&hr[0] * sw;
    f32x4 a1 = *(const f32x4*)&hr[4] * sw;

    int e0 = off[node], e1 = off[node + 1];
    for (int e = e0; e < e1; ++e) {
        int s   = csrc[e];
        float w = cw[e];
        const float* p = h + (size_t)s * HID + c0;
        a0 += *(const f32x4*)&p[0] * w;
        a1 += *(const f32x4*)&p[4] * w;
    }
    a0 += *(const f32x4*)&bias[c0];
    a1 += *(const f32x4*)&bias[c0 + 4];
#pragma unroll
    for (int j = 0; j < 4; ++j) {
        if (a0[j] < 0.f) a0[j] = 0.f;
        if (a1[j] < 0.f) a1[j] = 0.f;
    }

    if (LAST) {
        *(f32x4*)&x3[(size_t)node * HID + c0]     = a0;
        *(f32x4*)&x3[(size_t)node * HID + c0 + 4] = a1;
    } else {
        float v[8] = {a0[0], a0[1], a0[2], a0[3], a1[0], a1[1], a1[2], a1[3]};
        bf16x8 hi, lo;
#pragma unroll
        for (int j = 0; j < 8; ++j) {
            bf16_t hh = (bf16_t)v[j];
            hi[j] = hh;
            lo[j] = (bf16_t)(v[j] - (float)hh);
        }
        *(bf16x8*)&xh[(size_t)node * HID + c0] = hi;
        *(bf16x8*)&xl[(size_t)node * HID + c0] = lo;
    }
}

// ---------------------------------------------------------------------------
// Pooling: pooled[g][c] += x3[n][c] for batch[n]==g (batch sorted, run-flush)
// ---------------------------------------------------------------------------
__global__ void pool_k(const float* __restrict__ x3, const int* __restrict__ batch,
                       float* __restrict__ pooled) {
    int t  = threadIdx.x;            // 256: cols t and t+256
    int n0 = blockIdx.x * 50;
    int nend = min(n0 + 50, N_NODES);
    float acc0 = 0.f, acc1 = 0.f;
    int cur = -1;
    for (int n = n0; n < nend; ++n) {
        int g = batch[n];
        if (g != cur) {
            if (cur >= 0) {
                atomicAdd(&pooled[cur * HID + t], acc0);
                atomicAdd(&pooled[cur * HID + t + 256], acc1);
            }
            cur = g; acc0 = 0.f; acc1 = 0.f;
        }
        acc0 += x3[(size_t)n * HID + t];
        acc1 += x3[(size_t)n * HID + t + 256];
    }
    if (cur >= 0) {
        atomicAdd(&pooled[cur * HID + t], acc0);
        atomicAdd(&pooled[cur * HID + t + 256], acc1);
    }
}

// ---------------------------------------------------------------------------
// Head: logits = pooled @ lin_w + lin_b ; log_softmax. One wave per graph.
// ---------------------------------------------------------------------------
__global__ __launch_bounds__(64) void head_k(const float* __restrict__ pooled,
                                             const float* __restrict__ lw,
                                             const float* __restrict__ lb,
                                             float* __restrict__ out) {
    int g = blockIdx.x, l = threadIdx.x;
    float lg[10];
#pragma unroll
    for (int c = 0; c < N_CLASSES; ++c) {
        float s = 0.f;
        for (int k = l; k < HID; k += 64) s += pooled[g * HID + k] * lw[k * N_CLASSES + c];
        for (int o2 = 32; o2 > 0; o2 >>= 1) s += __shfl_down(s, o2);
        lg[c] = s;
    }
    if (l == 0) {
        float mx = -1e30f;
#pragma unroll
        for (int c = 0; c < N_CLASSES; ++c) { lg[c] += lb[c]; mx = fmaxf(mx, lg[c]); }
        float se = 0.f;
#pragma unroll
        for (int c = 0; c < N_CLASSES; ++c) se += expf(lg[c] - mx);
        float lse = logf(se);
#pragma unroll
        for (int c = 0; c < N_CLASSES; ++c) out[g * N_CLASSES + c] = lg[c] - mx - lse;
    }
}

// ---------------------------------------------------------------------------
extern "C" void kernel_launch(void* const* d_in, const int* in_sizes, int n_in,
                              void* d_out, int out_size, void* d_ws, size_t ws_size,
                              hipStream_t stream) {
    const float* x     = (const float*)d_in[0];
    const int*   ei    = (const int*)d_in[1];
    const int*   batch = (const int*)d_in[2];
    const float* Ws    = (const float*)d_in[3];
    const float* bs    = (const float*)d_in[4];
    const float* lw    = (const float*)d_in[5];
    const float* lb    = (const float*)d_in[6];
    float*       out   = (float*)d_out;
    const int E = in_sizes[1] / 2;
    const int* erow = ei;       // edge_index[0] = source
    const int* ecol = ei + E;   // edge_index[1] = target (aggregation index)

    char* p = (char*)d_ws;
    auto take = [&](size_t bytes) {
        char* q = p;
        p += (bytes + 255) & ~(size_t)255;
        return q;
    };
    bf16_t* xh    = (bf16_t*)take((size_t)MPAD * HID * 2);
    bf16_t* xl    = (bf16_t*)take((size_t)MPAD * HID * 2);
    float*  hbuf  = (float*) take((size_t)MPAD * HID * 4);
    float*  x3    = (float*) take((size_t)N_NODES * HID * 4);
    bf16_t* whT   = (bf16_t*)take((size_t)3 * HID * HID * 2);
    bf16_t* wlT   = (bf16_t*)take((size_t)3 * HID * HID * 2);
    float*  dinv  = (float*) take((size_t)N_NODES * 4);
    int*    cnt   = (int*)   take((size_t)N_NODES * 4);
    int*    off   = (int*)   take((size_t)(N_NODES + 1) * 4);
    int*    cur   = (int*)   take((size_t)N_NODES * 4);
    int*    csrc  = (int*)   take((size_t)E * 4);
    float*  cw    = (float*) take((size_t)E * 4);
    float*  pooled= (float*) take((size_t)N_GRAPHS * HID * 4);

    (void)hipMemsetAsync(cnt, 0, (size_t)N_NODES * 4, stream);
    (void)hipMemsetAsync(cur, 0, (size_t)N_NODES * 4, stream);
    (void)hipMemsetAsync(pooled, 0, (size_t)N_GRAPHS * HID * 4, stream);
    (void)hipMemsetAsync(xh + (size_t)N_NODES * HID, 0, (size_t)(MPAD - N_NODES) * HID * 2, stream);
    (void)hipMemsetAsync(xl + (size_t)N_NODES * HID, 0, (size_t)(MPAD - N_NODES) * HID * 2, stream);

    conv_x<<<(N_NODES * HID) / (256 * 8), 256, 0, stream>>>(x, xh, xl);
    conv_w<<<(3 * HID * HID) / 256, 256, 0, stream>>>(Ws, whT, wlT);
    count_deg<<<(E + 255) / 256, 256, 0, stream>>>(ecol, cnt, E);
    dinv_k<<<(N_NODES + 255) / 256, 256, 0, stream>>>(cnt, dinv);
    scan_k<<<1, 1024, 0, stream>>>(cnt, off);
    scatter_k<<<(E + 255) / 256, 256, 0, stream>>>(erow, ecol, off, cur, dinv, csrc, cw, E);

    for (int lyr = 0; lyr < 3; ++lyr) {
        gemm3<<<dim3(MPAD / 128, HID / 128), 256, 0, stream>>>(
            xh, xl, whT + (size_t)lyr * HID * HID, wlT + (size_t)lyr * HID * HID, hbuf);
        if (lyr < 2)
            agg_k<false><<<(N_NODES + 3) / 4, 256, 0, stream>>>(
                hbuf, off, csrc, cw, dinv, bs + lyr * HID, xh, xl, nullptr);
        else
            agg_k<true><<<(N_NODES + 3) / 4, 256, 0, stream>>>(
                hbuf, off, csrc, cw, dinv, bs + lyr * HID, nullptr, nullptr, x3);
    }
    pool_k<<<200, 256, 0, stream>>>(x3, batch, pooled);
    head_k<<<N_GRAPHS, 64, 0, stream>>>(pooled, lw, lb, out);
}

// Round 3
// 259.816 us; speedup vs baseline: 1.2968x; 1.2968x over previous
//
#include <hip/hip_runtime.h>

#define N_NODES 10000
#define HID 512
#define MPAD 10112          // 79 * 128
#define N_GRAPHS 64
#define N_CLASSES 10

typedef __bf16 bf16_t;
typedef __bf16 bf16x8 __attribute__((ext_vector_type(8)));
typedef float  f32x4  __attribute__((ext_vector_type(4)));

// ---------------------------------------------------------------------------
// async global->LDS 16B copy (gfx950). LDS dest is wave-uniform base + lane*16;
// our chunk->thread mapping is linear so per-lane dst pointers satisfy that.
// ---------------------------------------------------------------------------
__device__ __forceinline__ void gload16(const bf16_t* g, bf16_t* l) {
    __builtin_amdgcn_global_load_lds(
        (const __attribute__((address_space(1))) void*)g,
        (__attribute__((address_space(3))) void*)l,
        16, 0, 0);
}

// ---------------------------------------------------------------------------
// Input conversion: x (fp32) -> bf16 hi/lo pair (3-term split GEMM precision)
// ---------------------------------------------------------------------------
__global__ void conv_x(const float* __restrict__ x,
                       bf16_t* __restrict__ xh, bf16_t* __restrict__ xl) {
    int idx = (blockIdx.x * 256 + threadIdx.x) * 8;   // < N_NODES*HID
    f32x4 v0 = *(const f32x4*)&x[idx];
    f32x4 v1 = *(const f32x4*)&x[idx + 4];
    float v[8] = {v0[0], v0[1], v0[2], v0[3], v1[0], v1[1], v1[2], v1[3]};
    bf16x8 hi, lo;
#pragma unroll
    for (int j = 0; j < 8; ++j) {
        bf16_t h = (bf16_t)v[j];
        hi[j] = h;
        lo[j] = (bf16_t)(v[j] - (float)h);
    }
    *(bf16x8*)&xh[idx] = hi;
    *(bf16x8*)&xl[idx] = lo;
}

// W [3][512][512] row-major (W[l][k][j]) -> transposed bf16 hi/lo: WT[l][j][k]
__global__ void conv_w(const float* __restrict__ W,
                       bf16_t* __restrict__ whT, bf16_t* __restrict__ wlT) {
    int o   = blockIdx.x * 256 + threadIdx.x;  // < 3*512*512, output-indexed
    int lyr = o >> 18;
    int rem = o & 262143;
    int j   = rem >> 9;
    int k   = rem & 511;
    float v = W[(lyr << 18) + (k << 9) + j];
    bf16_t h = (bf16_t)v;
    whT[o] = h;
    wlT[o] = (bf16_t)(v - (float)h);
}

// ---------------------------------------------------------------------------
// Degree + CSR build (grouped by target col), no fp32 atomics in hot path
// ---------------------------------------------------------------------------
__global__ void count_deg(const int* __restrict__ col, int* __restrict__ cnt, int E) {
    int e = blockIdx.x * 256 + threadIdx.x;
    if (e < E) atomicAdd(&cnt[col[e]], 1);
}

__global__ void dinv_k(const int* __restrict__ cnt, float* __restrict__ dinv) {
    int n = blockIdx.x * 256 + threadIdx.x;
    if (n < N_NODES) dinv[n] = rsqrtf(1.0f + (float)cnt[n]);  // +1 self-loop
}

__global__ __launch_bounds__(1024) void scan_k(const int* __restrict__ cnt,
                                               int* __restrict__ off) {
    __shared__ int s[1024];
    int t = threadIdx.x;
    int base = t * 10;
    int loc[10];
    int sum = 0;
#pragma unroll
    for (int j = 0; j < 10; ++j) {
        int n = base + j;
        int v = (n < N_NODES) ? cnt[n] : 0;
        loc[j] = sum;
        sum += v;
    }
    s[t] = sum;
    __syncthreads();
    for (int o = 1; o < 1024; o <<= 1) {
        int v = (t >= o) ? s[t - o] : 0;
        __syncthreads();
        s[t] += v;
        __syncthreads();
    }
    int pre = (t > 0) ? s[t - 1] : 0;
#pragma unroll
    for (int j = 0; j < 10; ++j) {
        int n = base + j;
        if (n <= N_NODES) off[n] = pre + loc[j];
    }
}

__global__ void scatter_k(const int* __restrict__ row, const int* __restrict__ col,
                          const int* __restrict__ off, int* __restrict__ cursor,
                          const float* __restrict__ dinv,
                          int* __restrict__ csrc, float* __restrict__ cw, int E) {
    int e = blockIdx.x * 256 + threadIdx.x;
    if (e >= E) return;
    int c = col[e], r = row[e];
    int p = off[c] + atomicAdd(&cursor[c], 1);
    csrc[p] = r;
    cw[p]   = dinv[r] * dinv[c];
}

// ---------------------------------------------------------------------------
// GEMM: hh[MPAD][512] = bf16( (xh+xl) @ (Wh+Wl) )  via 3-term bf16 MFMA split
// 128x128 tile, 4 waves (2x2), 64x64/wave, BK=32, global_load_lds staging
// ---------------------------------------------------------------------------
__global__ __launch_bounds__(256) void gemm3(
    const bf16_t* __restrict__ xh, const bf16_t* __restrict__ xl,
    const bf16_t* __restrict__ wh, const bf16_t* __restrict__ wl,  // [512][512] = W^T[j][k]
    bf16_t* __restrict__ hh)
{
    __shared__ alignas(16) bf16_t sAh[128 * 32];
    __shared__ alignas(16) bf16_t sAl[128 * 32];
    __shared__ alignas(16) bf16_t sBh[128 * 32];
    __shared__ alignas(16) bf16_t sBl[128 * 32];

    const int t  = threadIdx.x;
    const int l  = t & 63;
    const int wv = t >> 6;
    const int wr = wv >> 1;   // 0..1
    const int wc = wv & 1;    // 0..1
    const int m0 = blockIdx.x * 128;
    const int n0 = blockIdx.y * 128;

    f32x4 acc[4][4];
#pragma unroll
    for (int m = 0; m < 4; ++m)
#pragma unroll
        for (int n = 0; n < 4; ++n) acc[m][n] = (f32x4){0.f, 0.f, 0.f, 0.f};

    const int lr  = l & 15;
    const int kgr = (l >> 4) * 8;   // k-group start within BK=32

    for (int kk = 0; kk < HID; kk += 32) {
        __syncthreads();  // previous iter's readers done before overwrite
#pragma unroll
        for (int i = 0; i < 2; ++i) {
            int c  = t + i * 256;          // 16B chunk index, 0..511
            int r  = c >> 2;               // tile row (64B per row of 32 bf16)
            int ce = (c & 3) * 8;          // element offset within row
            size_t gA = (size_t)(m0 + r) * HID + kk + ce;
            size_t gB = (size_t)(n0 + r) * HID + kk + ce;
            bf16_t* dA = &sAh[0] + (size_t)c * 8;   // linear: chunk c -> bytes [16c,16c+16)
            bf16_t* dAl= &sAl[0] + (size_t)c * 8;
            bf16_t* dB = &sBh[0] + (size_t)c * 8;
            bf16_t* dBl= &sBl[0] + (size_t)c * 8;
            gload16(&xh[gA], dA);
            gload16(&xl[gA], dAl);
            gload16(&wh[gB], dB);
            gload16(&wl[gB], dBl);
        }
        __syncthreads();

        bf16x8 ah[4], al[4], bh[4], bl[4];
#pragma unroll
        for (int m = 0; m < 4; ++m) {
            int row = wr * 64 + m * 16 + lr;
            ah[m] = *(const bf16x8*)&sAh[row * 32 + kgr];
            al[m] = *(const bf16x8*)&sAl[row * 32 + kgr];
        }
#pragma unroll
        for (int n = 0; n < 4; ++n) {
            int col = wc * 64 + n * 16 + lr;
            bh[n] = *(const bf16x8*)&sBh[col * 32 + kgr];
            bl[n] = *(const bf16x8*)&sBl[col * 32 + kgr];
        }
#pragma unroll
        for (int m = 0; m < 4; ++m)
#pragma unroll
            for (int n = 0; n < 4; ++n) {
                acc[m][n] = __builtin_amdgcn_mfma_f32_16x16x32_bf16(ah[m], bh[n], acc[m][n], 0, 0, 0);
                acc[m][n] = __builtin_amdgcn_mfma_f32_16x16x32_bf16(al[m], bh[n], acc[m][n], 0, 0, 0);
                acc[m][n] = __builtin_amdgcn_mfma_f32_16x16x32_bf16(ah[m], bl[n], acc[m][n], 0, 0, 0);
            }
    }

    // C/D layout (m89-verified): col = l&15, row = (l>>4)*4 + r
    const int rq = (l >> 4) * 4;
#pragma unroll
    for (int m = 0; m < 4; ++m) {
        int row = m0 + wr * 64 + m * 16 + rq;
#pragma unroll
        for (int n = 0; n < 4; ++n) {
            int col = n0 + wc * 64 + n * 16 + lr;
#pragma unroll
            for (int r = 0; r < 4; ++r)
                hh[(size_t)(row + r) * HID + col] = (bf16_t)acc[m][n][r];
        }
    }
}

// ---------------------------------------------------------------------------
// Aggregation: out[n] = relu( sum_{e->n} w_e * hh[src_e] + dinv[n]^2 * hh[n] + b )
// hh is bf16 (halves the gather table: 10.4 MB); accumulate fp32.
// one wave per node, lane owns 8 contiguous cols (one bf16x8 load per row)
// ---------------------------------------------------------------------------
template <bool LAST>
__global__ __launch_bounds__(256) void agg_k(
    const bf16_t* __restrict__ hh, const int* __restrict__ off,
    const int* __restrict__ csrc, const float* __restrict__ cw,
    const float* __restrict__ dinv, const float* __restrict__ bias,
    bf16_t* __restrict__ xh, bf16_t* __restrict__ xl, float* __restrict__ x3)
{
    int node = blockIdx.x * 4 + (threadIdx.x >> 6);
    if (node >= N_NODES) return;
    int l  = threadIdx.x & 63;
    int c0 = l * 8;

    float dn = dinv[node];
    float sw = dn * dn;
    float a[8];
    {
        bf16x8 sv = *(const bf16x8*)&hh[(size_t)node * HID + c0];
#pragma unroll
        for (int j = 0; j < 8; ++j) a[j] = (float)sv[j] * sw;
    }

    int e0 = off[node], e1 = off[node + 1];
    for (int e = e0; e < e1; ++e) {
        int s   = csrc[e];
        float w = cw[e];
        bf16x8 v = *(const bf16x8*)&hh[(size_t)s * HID + c0];
#pragma unroll
        for (int j = 0; j < 8; ++j) a[j] += (float)v[j] * w;
    }
#pragma unroll
    for (int j = 0; j < 8; ++j) {
        a[j] += bias[c0 + j];
        if (a[j] < 0.f) a[j] = 0.f;
    }

    if (LAST) {
        f32x4 o0 = {a[0], a[1], a[2], a[3]};
        f32x4 o1 = {a[4], a[5], a[6], a[7]};
        *(f32x4*)&x3[(size_t)node * HID + c0]     = o0;
        *(f32x4*)&x3[(size_t)node * HID + c0 + 4] = o1;
    } else {
        bf16x8 hi, lo;
#pragma unroll
        for (int j = 0; j < 8; ++j) {
            bf16_t hb = (bf16_t)a[j];
            hi[j] = hb;
            lo[j] = (bf16_t)(a[j] - (float)hb);
        }
        *(bf16x8*)&xh[(size_t)node * HID + c0] = hi;
        *(bf16x8*)&xl[(size_t)node * HID + c0] = lo;
    }
}

// ---------------------------------------------------------------------------
// Pooling: pooled[g][c] += x3[n][c] for batch[n]==g (batch sorted, run-flush)
// ---------------------------------------------------------------------------
__global__ void pool_k(const float* __restrict__ x3, const int* __restrict__ batch,
                       float* __restrict__ pooled) {
    int t  = threadIdx.x;            // 256: cols t and t+256
    int n0 = blockIdx.x * 20;
    int nend = min(n0 + 20, N_NODES);
    float acc0 = 0.f, acc1 = 0.f;
    int cur = -1;
    for (int n = n0; n < nend; ++n) {
        int g = batch[n];
        if (g != cur) {
            if (cur >= 0) {
                atomicAdd(&pooled[cur * HID + t], acc0);
                atomicAdd(&pooled[cur * HID + t + 256], acc1);
            }
            cur = g; acc0 = 0.f; acc1 = 0.f;
        }
        acc0 += x3[(size_t)n * HID + t];
        acc1 += x3[(size_t)n * HID + t + 256];
    }
    if (cur >= 0) {
        atomicAdd(&pooled[cur * HID + t], acc0);
        atomicAdd(&pooled[cur * HID + t + 256], acc1);
    }
}

// ---------------------------------------------------------------------------
// Head: logits = pooled @ lin_w + lin_b ; log_softmax. One wave per graph.
// ---------------------------------------------------------------------------
__global__ __launch_bounds__(64) void head_k(const float* __restrict__ pooled,
                                             const float* __restrict__ lw,
                                             const float* __restrict__ lb,
                                             float* __restrict__ out) {
    int g = blockIdx.x, l = threadIdx.x;
    float lg[10];
#pragma unroll
    for (int c = 0; c < N_CLASSES; ++c) {
        float s = 0.f;
        for (int k = l; k < HID; k += 64) s += pooled[g * HID + k] * lw[k * N_CLASSES + c];
        for (int o2 = 32; o2 > 0; o2 >>= 1) s += __shfl_down(s, o2);
        lg[c] = s;
    }
    if (l == 0) {
        float mx = -1e30f;
#pragma unroll
        for (int c = 0; c < N_CLASSES; ++c) { lg[c] += lb[c]; mx = fmaxf(mx, lg[c]); }
        float se = 0.f;
#pragma unroll
        for (int c = 0; c < N_CLASSES; ++c) se += expf(lg[c] - mx);
        float lse = logf(se);
#pragma unroll
        for (int c = 0; c < N_CLASSES; ++c) out[g * N_CLASSES + c] = lg[c] - mx - lse;
    }
}

// ---------------------------------------------------------------------------
extern "C" void kernel_launch(void* const* d_in, const int* in_sizes, int n_in,
                              void* d_out, int out_size, void* d_ws, size_t ws_size,
                              hipStream_t stream) {
    const float* x     = (const float*)d_in[0];
    const int*   ei    = (const int*)d_in[1];
    const int*   batch = (const int*)d_in[2];
    const float* Ws    = (const float*)d_in[3];
    const float* bs    = (const float*)d_in[4];
    const float* lw    = (const float*)d_in[5];
    const float* lb    = (const float*)d_in[6];
    float*       out   = (float*)d_out;
    const int E = in_sizes[1] / 2;
    const int* erow = ei;       // edge_index[0] = source
    const int* ecol = ei + E;   // edge_index[1] = target (aggregation index)

    char* p = (char*)d_ws;
    auto take = [&](size_t bytes) {
        char* q = p;
        p += (bytes + 255) & ~(size_t)255;
        return q;
    };
    bf16_t* xh    = (bf16_t*)take((size_t)MPAD * HID * 2);
    bf16_t* xl    = (bf16_t*)take((size_t)MPAD * HID * 2);
    bf16_t* hh    = (bf16_t*)take((size_t)MPAD * HID * 2);
    float*  x3    = (float*) take((size_t)N_NODES * HID * 4);
    bf16_t* whT   = (bf16_t*)take((size_t)3 * HID * HID * 2);
    bf16_t* wlT   = (bf16_t*)take((size_t)3 * HID * HID * 2);
    float*  dinv  = (float*) take((size_t)N_NODES * 4);
    int*    cnt   = (int*)   take((size_t)N_NODES * 4);
    int*    off   = (int*)   take((size_t)(N_NODES + 1) * 4);
    int*    cur   = (int*)   take((size_t)N_NODES * 4);
    int*    csrc  = (int*)   take((size_t)E * 4);
    float*  cw    = (float*) take((size_t)E * 4);
    float*  pooled= (float*) take((size_t)N_GRAPHS * HID * 4);

    (void)hipMemsetAsync(cnt, 0, (size_t)N_NODES * 4, stream);
    (void)hipMemsetAsync(cur, 0, (size_t)N_NODES * 4, stream);
    (void)hipMemsetAsync(pooled, 0, (size_t)N_GRAPHS * HID * 4, stream);
    (void)hipMemsetAsync(xh + (size_t)N_NODES * HID, 0, (size_t)(MPAD - N_NODES) * HID * 2, stream);
    (void)hipMemsetAsync(xl + (size_t)N_NODES * HID, 0, (size_t)(MPAD - N_NODES) * HID * 2, stream);

    conv_x<<<(N_NODES * HID) / (256 * 8), 256, 0, stream>>>(x, xh, xl);
    conv_w<<<(3 * HID * HID) / 256, 256, 0, stream>>>(Ws, whT, wlT);
    count_deg<<<(E + 255) / 256, 256, 0, stream>>>(ecol, cnt, E);
    dinv_k<<<(N_NODES + 255) / 256, 256, 0, stream>>>(cnt, dinv);
    scan_k<<<1, 1024, 0, stream>>>(cnt, off);
    scatter_k<<<(E + 255) / 256, 256, 0, stream>>>(erow, ecol, off, cur, dinv, csrc, cw, E);

    for (int lyr = 0; lyr < 3; ++lyr) {
        gemm3<<<dim3(MPAD / 128, HID / 128), 256, 0, stream>>>(
            xh, xl, whT + (size_t)lyr * HID * HID, wlT + (size_t)lyr * HID * HID, hh);
        if (lyr < 2)
            agg_k<false><<<(N_NODES + 3) / 4, 256, 0, stream>>>(
                hh, off, csrc, cw, dinv, bs + lyr * HID, xh, xl, nullptr);
        else
            agg_k<true><<<(N_NODES + 3) / 4, 256, 0, stream>>>(
                hh, off, csrc, cw, dinv, bs + lyr * HID, nullptr, nullptr, x3);
    }
    pool_k<<<500, 256, 0, stream>>>(x3, batch, pooled);
    head_k<<<N_GRAPHS, 64, 0, stream>>>(pooled, lw, lb, out);
}

// Round 4
// 253.077 us; speedup vs baseline: 1.3313x; 1.0266x over previous
//
#include <hip/hip_runtime.h>

#define N_NODES 10000
#define HID 512
#define MPAD 10112          // 158 * 64
#define N_GRAPHS 64
#define N_CLASSES 10

typedef __bf16 bf16_t;
typedef __bf16 bf16x8 __attribute__((ext_vector_type(8)));
typedef float  f32x4  __attribute__((ext_vector_type(4)));

// ---------------------------------------------------------------------------
// async global->LDS 16B copy (gfx950). LDS dest is wave-uniform base + lane*16;
// our chunk->thread mapping is linear so per-lane dst pointers satisfy that.
// ---------------------------------------------------------------------------
__device__ __forceinline__ void gload16(const bf16_t* g, bf16_t* l) {
    __builtin_amdgcn_global_load_lds(
        (const __attribute__((address_space(1))) void*)g,
        (__attribute__((address_space(3))) void*)l,
        16, 0, 0);
}

// ---------------------------------------------------------------------------
// Input conversion: x (fp32) -> bf16 hi/lo pair (3-term split GEMM precision)
// ---------------------------------------------------------------------------
__global__ void conv_x(const float* __restrict__ x,
                       bf16_t* __restrict__ xh, bf16_t* __restrict__ xl) {
    int idx = (blockIdx.x * 256 + threadIdx.x) * 8;   // < N_NODES*HID
    f32x4 v0 = *(const f32x4*)&x[idx];
    f32x4 v1 = *(const f32x4*)&x[idx + 4];
    float v[8] = {v0[0], v0[1], v0[2], v0[3], v1[0], v1[1], v1[2], v1[3]};
    bf16x8 hi, lo;
#pragma unroll
    for (int j = 0; j < 8; ++j) {
        bf16_t h = (bf16_t)v[j];
        hi[j] = h;
        lo[j] = (bf16_t)(v[j] - (float)h);
    }
    *(bf16x8*)&xh[idx] = hi;
    *(bf16x8*)&xl[idx] = lo;
}

// W [3][512][512] row-major (W[l][k][j]) -> transposed bf16 hi/lo: WT[l][j][k]
__global__ void conv_w(const float* __restrict__ W,
                       bf16_t* __restrict__ whT, bf16_t* __restrict__ wlT) {
    int o   = blockIdx.x * 256 + threadIdx.x;  // < 3*512*512, output-indexed
    int lyr = o >> 18;
    int rem = o & 262143;
    int j   = rem >> 9;
    int k   = rem & 511;
    float v = W[(lyr << 18) + (k << 9) + j];
    bf16_t h = (bf16_t)v;
    whT[o] = h;
    wlT[o] = (bf16_t)(v - (float)h);
}

// ---------------------------------------------------------------------------
// Degree + CSR build (grouped by target col), no fp32 atomics in hot path
// ---------------------------------------------------------------------------
__global__ void count_deg(const int* __restrict__ col, int* __restrict__ cnt, int E) {
    int e = blockIdx.x * 256 + threadIdx.x;
    if (e < E) atomicAdd(&cnt[col[e]], 1);
}

__global__ void dinv_k(const int* __restrict__ cnt, float* __restrict__ dinv) {
    int n = blockIdx.x * 256 + threadIdx.x;
    if (n < N_NODES) dinv[n] = rsqrtf(1.0f + (float)cnt[n]);  // +1 self-loop
}

__global__ __launch_bounds__(1024) void scan_k(const int* __restrict__ cnt,
                                               int* __restrict__ off) {
    __shared__ int s[1024];
    int t = threadIdx.x;
    int base = t * 10;
    int loc[10];
    int sum = 0;
#pragma unroll
    for (int j = 0; j < 10; ++j) {
        int n = base + j;
        int v = (n < N_NODES) ? cnt[n] : 0;
        loc[j] = sum;
        sum += v;
    }
    s[t] = sum;
    __syncthreads();
    for (int o = 1; o < 1024; o <<= 1) {
        int v = (t >= o) ? s[t - o] : 0;
        __syncthreads();
        s[t] += v;
        __syncthreads();
    }
    int pre = (t > 0) ? s[t - 1] : 0;
#pragma unroll
    for (int j = 0; j < 10; ++j) {
        int n = base + j;
        if (n <= N_NODES) off[n] = pre + loc[j];
    }
}

// packed edge record: .x = src index, .y = float bits of weight
__global__ void scatter_k(const int* __restrict__ row, const int* __restrict__ col,
                          const int* __restrict__ off, int* __restrict__ cursor,
                          const float* __restrict__ dinv,
                          int2* __restrict__ epk, int E) {
    int e = blockIdx.x * 256 + threadIdx.x;
    if (e >= E) return;
    int c = col[e], r = row[e];
    int p = off[c] + atomicAdd(&cursor[c], 1);
    float w = dinv[r] * dinv[c];
    epk[p] = make_int2(r, __float_as_int(w));
}

// ---------------------------------------------------------------------------
// GEMM: hh[MPAD][512] = bf16( (xh+xl) @ (Wh+Wl) )  via 3-term bf16 MFMA split
// 64x128 tile, 4 waves (2x2), 32x64/wave, BK=32, global_load_lds staging.
// grid (4, 158): N-tile fastest so A-panel sharers are temporally adjacent.
// ---------------------------------------------------------------------------
__global__ __launch_bounds__(256) void gemm3(
    const bf16_t* __restrict__ xh, const bf16_t* __restrict__ xl,
    const bf16_t* __restrict__ wh, const bf16_t* __restrict__ wl,  // [512][512] = W^T[j][k]
    bf16_t* __restrict__ hh)
{
    __shared__ alignas(16) bf16_t sAh[64 * 32];
    __shared__ alignas(16) bf16_t sAl[64 * 32];
    __shared__ alignas(16) bf16_t sBh[128 * 32];
    __shared__ alignas(16) bf16_t sBl[128 * 32];

    const int t  = threadIdx.x;
    const int l  = t & 63;
    const int wv = t >> 6;
    const int wr = wv >> 1;   // 0..1: 32-row half of M-tile
    const int wc = wv & 1;    // 0..1: 64-col half of N-tile
    const int n0 = blockIdx.x * 128;
    const int m0 = blockIdx.y * 64;

    f32x4 acc[2][4];
#pragma unroll
    for (int m = 0; m < 2; ++m)
#pragma unroll
        for (int n = 0; n < 4; ++n) acc[m][n] = (f32x4){0.f, 0.f, 0.f, 0.f};

    const int lr  = l & 15;
    const int kgr = (l >> 4) * 8;        // k-group start within BK=32
    const int srow = t >> 2;             // staging row 0..63
    const int sce  = (t & 3) * 8;        // staging element offset within row

    for (int kk = 0; kk < HID; kk += 32) {
        __syncthreads();  // previous iter's readers done before overwrite
        {
            size_t gA  = (size_t)(m0 + srow) * HID + kk + sce;
            size_t gB0 = (size_t)(n0 + srow) * HID + kk + sce;
            size_t gB1 = (size_t)(n0 + 64 + srow) * HID + kk + sce;
            gload16(&xh[gA],  &sAh[t * 8]);
            gload16(&xl[gA],  &sAl[t * 8]);
            gload16(&wh[gB0], &sBh[t * 8]);
            gload16(&wl[gB0], &sBl[t * 8]);
            gload16(&wh[gB1], &sBh[(t + 256) * 8]);
            gload16(&wl[gB1], &sBl[(t + 256) * 8]);
        }
        __syncthreads();

        bf16x8 ah[2], al[2], bh[4], bl[4];
#pragma unroll
        for (int m = 0; m < 2; ++m) {
            int row = wr * 32 + m * 16 + lr;
            ah[m] = *(const bf16x8*)&sAh[row * 32 + kgr];
            al[m] = *(const bf16x8*)&sAl[row * 32 + kgr];
        }
#pragma unroll
        for (int n = 0; n < 4; ++n) {
            int col = wc * 64 + n * 16 + lr;
            bh[n] = *(const bf16x8*)&sBh[col * 32 + kgr];
            bl[n] = *(const bf16x8*)&sBl[col * 32 + kgr];
        }
#pragma unroll
        for (int m = 0; m < 2; ++m)
#pragma unroll
            for (int n = 0; n < 4; ++n) {
                acc[m][n] = __builtin_amdgcn_mfma_f32_16x16x32_bf16(ah[m], bh[n], acc[m][n], 0, 0, 0);
                acc[m][n] = __builtin_amdgcn_mfma_f32_16x16x32_bf16(al[m], bh[n], acc[m][n], 0, 0, 0);
                acc[m][n] = __builtin_amdgcn_mfma_f32_16x16x32_bf16(ah[m], bl[n], acc[m][n], 0, 0, 0);
            }
    }

    // C/D layout (m89-verified): col = l&15, row = (l>>4)*4 + r
    const int rq = (l >> 4) * 4;
#pragma unroll
    for (int m = 0; m < 2; ++m) {
        int row = m0 + wr * 32 + m * 16 + rq;
#pragma unroll
        for (int n = 0; n < 4; ++n) {
            int col = n0 + wc * 64 + n * 16 + lr;
#pragma unroll
            for (int r = 0; r < 4; ++r)
                hh[(size_t)(row + r) * HID + col] = (bf16_t)acc[m][n][r];
        }
    }
}

// ---------------------------------------------------------------------------
// Aggregation: out[n] = relu( sum_{e->n} w_e * hh[src_e] + dinv[n]^2 * hh[n] + b )
// hh is bf16 (10.4 MB gather table); accumulate fp32.
// one wave per node, lane owns 8 contiguous cols (one bf16x8 load per row)
// ---------------------------------------------------------------------------
template <bool LAST>
__global__ __launch_bounds__(256) void agg_k(
    const bf16_t* __restrict__ hh, const int* __restrict__ off,
    const int2* __restrict__ epk,
    const float* __restrict__ dinv, const float* __restrict__ bias,
    bf16_t* __restrict__ xh, bf16_t* __restrict__ xl, float* __restrict__ x3)
{
    int node = blockIdx.x * 4 + (threadIdx.x >> 6);
    if (node >= N_NODES) return;
    int l  = threadIdx.x & 63;
    int c0 = l * 8;

    float dn = dinv[node];
    float sw = dn * dn;
    float a[8];
    {
        bf16x8 sv = *(const bf16x8*)&hh[(size_t)node * HID + c0];
#pragma unroll
        for (int j = 0; j < 8; ++j) a[j] = (float)sv[j] * sw;
    }

    int e0 = off[node], e1 = off[node + 1];
    for (int e = e0; e < e1; ++e) {
        int2 ed = epk[e];
        float w = __int_as_float(ed.y);
        bf16x8 v = *(const bf16x8*)&hh[(size_t)ed.x * HID + c0];
#pragma unroll
        for (int j = 0; j < 8; ++j) a[j] += (float)v[j] * w;
    }
#pragma unroll
    for (int j = 0; j < 8; ++j) {
        a[j] += bias[c0 + j];
        if (a[j] < 0.f) a[j] = 0.f;
    }

    if (LAST) {
        f32x4 o0 = {a[0], a[1], a[2], a[3]};
        f32x4 o1 = {a[4], a[5], a[6], a[7]};
        *(f32x4*)&x3[(size_t)node * HID + c0]     = o0;
        *(f32x4*)&x3[(size_t)node * HID + c0 + 4] = o1;
    } else {
        bf16x8 hi, lo;
#pragma unroll
        for (int j = 0; j < 8; ++j) {
            bf16_t hb = (bf16_t)a[j];
            hi[j] = hb;
            lo[j] = (bf16_t)(a[j] - (float)hb);
        }
        *(bf16x8*)&xh[(size_t)node * HID + c0] = hi;
        *(bf16x8*)&xl[(size_t)node * HID + c0] = lo;
    }
}

// ---------------------------------------------------------------------------
// Pooling: pooled[g][c] += x3[n][c] for batch[n]==g (batch sorted, run-flush)
// ---------------------------------------------------------------------------
__global__ void pool_k(const float* __restrict__ x3, const int* __restrict__ batch,
                       float* __restrict__ pooled) {
    int t  = threadIdx.x;            // 256: cols t and t+256
    int n0 = blockIdx.x * 20;
    int nend = min(n0 + 20, N_NODES);
    float acc0 = 0.f, acc1 = 0.f;
    int cur = -1;
    for (int n = n0; n < nend; ++n) {
        int g = batch[n];
        if (g != cur) {
            if (cur >= 0) {
                atomicAdd(&pooled[cur * HID + t], acc0);
                atomicAdd(&pooled[cur * HID + t + 256], acc1);
            }
            cur = g; acc0 = 0.f; acc1 = 0.f;
        }
        acc0 += x3[(size_t)n * HID + t];
        acc1 += x3[(size_t)n * HID + t + 256];
    }
    if (cur >= 0) {
        atomicAdd(&pooled[cur * HID + t], acc0);
        atomicAdd(&pooled[cur * HID + t + 256], acc1);
    }
}

// ---------------------------------------------------------------------------
// Head: logits = pooled @ lin_w + lin_b ; log_softmax. One wave per graph.
// ---------------------------------------------------------------------------
__global__ __launch_bounds__(64) void head_k(const float* __restrict__ pooled,
                                             const float* __restrict__ lw,
                                             const float* __restrict__ lb,
                                             float* __restrict__ out) {
    int g = blockIdx.x, l = threadIdx.x;
    float lg[10];
#pragma unroll
    for (int c = 0; c < N_CLASSES; ++c) {
        float s = 0.f;
        for (int k = l; k < HID; k += 64) s += pooled[g * HID + k] * lw[k * N_CLASSES + c];
        for (int o2 = 32; o2 > 0; o2 >>= 1) s += __shfl_down(s, o2);
        lg[c] = s;
    }
    if (l == 0) {
        float mx = -1e30f;
#pragma unroll
        for (int c = 0; c < N_CLASSES; ++c) { lg[c] += lb[c]; mx = fmaxf(mx, lg[c]); }
        float se = 0.f;
#pragma unroll
        for (int c = 0; c < N_CLASSES; ++c) se += expf(lg[c] - mx);
        float lse = logf(se);
#pragma unroll
        for (int c = 0; c < N_CLASSES; ++c) out[g * N_CLASSES + c] = lg[c] - mx - lse;
    }
}

// ---------------------------------------------------------------------------
extern "C" void kernel_launch(void* const* d_in, const int* in_sizes, int n_in,
                              void* d_out, int out_size, void* d_ws, size_t ws_size,
                              hipStream_t stream) {
    const float* x     = (const float*)d_in[0];
    const int*   ei    = (const int*)d_in[1];
    const int*   batch = (const int*)d_in[2];
    const float* Ws    = (const float*)d_in[3];
    const float* bs    = (const float*)d_in[4];
    const float* lw    = (const float*)d_in[5];
    const float* lb    = (const float*)d_in[6];
    float*       out   = (float*)d_out;
    const int E = in_sizes[1] / 2;
    const int* erow = ei;       // edge_index[0] = source
    const int* ecol = ei + E;   // edge_index[1] = target (aggregation index)

    char* p = (char*)d_ws;
    auto take = [&](size_t bytes) {
        char* q = p;
        p += (bytes + 255) & ~(size_t)255;
        return q;
    };
    bf16_t* xh    = (bf16_t*)take((size_t)MPAD * HID * 2);
    bf16_t* xl    = (bf16_t*)take((size_t)MPAD * HID * 2);
    bf16_t* hh    = (bf16_t*)take((size_t)MPAD * HID * 2);
    float*  x3    = (float*) take((size_t)N_NODES * HID * 4);
    bf16_t* whT   = (bf16_t*)take((size_t)3 * HID * HID * 2);
    bf16_t* wlT   = (bf16_t*)take((size_t)3 * HID * HID * 2);
    float*  dinv  = (float*) take((size_t)N_NODES * 4);
    int*    cnt   = (int*)   take((size_t)N_NODES * 4);
    int*    off   = (int*)   take((size_t)(N_NODES + 1) * 4);
    int*    cur   = (int*)   take((size_t)N_NODES * 4);
    int2*   epk   = (int2*)  take((size_t)E * 8);
    float*  pooled= (float*) take((size_t)N_GRAPHS * HID * 4);

    (void)hipMemsetAsync(cnt, 0, (size_t)N_NODES * 4, stream);
    (void)hipMemsetAsync(cur, 0, (size_t)N_NODES * 4, stream);
    (void)hipMemsetAsync(pooled, 0, (size_t)N_GRAPHS * HID * 4, stream);
    (void)hipMemsetAsync(xh + (size_t)N_NODES * HID, 0, (size_t)(MPAD - N_NODES) * HID * 2, stream);
    (void)hipMemsetAsync(xl + (size_t)N_NODES * HID, 0, (size_t)(MPAD - N_NODES) * HID * 2, stream);

    conv_x<<<(N_NODES * HID) / (256 * 8), 256, 0, stream>>>(x, xh, xl);
    conv_w<<<(3 * HID * HID) / 256, 256, 0, stream>>>(Ws, whT, wlT);
    count_deg<<<(E + 255) / 256, 256, 0, stream>>>(ecol, cnt, E);
    dinv_k<<<(N_NODES + 255) / 256, 256, 0, stream>>>(cnt, dinv);
    scan_k<<<1, 1024, 0, stream>>>(cnt, off);
    scatter_k<<<(E + 255) / 256, 256, 0, stream>>>(erow, ecol, off, cur, dinv, epk, E);

    for (int lyr = 0; lyr < 3; ++lyr) {
        gemm3<<<dim3(4, 158), 256, 0, stream>>>(
            xh, xl, whT + (size_t)lyr * HID * HID, wlT + (size_t)lyr * HID * HID, hh);
        if (lyr < 2)
            agg_k<false><<<(N_NODES + 3) / 4, 256, 0, stream>>>(
                hh, off, epk, dinv, bs + lyr * HID, xh, xl, nullptr);
        else
            agg_k<true><<<(N_NODES + 3) / 4, 256, 0, stream>>>(
                hh, off, epk, dinv, bs + lyr * HID, nullptr, nullptr, x3);
    }
    pool_k<<<500, 256, 0, stream>>>(x3, batch, pooled);
    head_k<<<N_GRAPHS, 64, 0, stream>>>(pooled, lw, lb, out);
}